// Round 20
// baseline (348.897 us; speedup 1.0000x reference)
//
#include <hip/hip_runtime.h>
#include <math.h>

#define Bn   64
#define Ln   4096
#define LQn  128
#define Dn   32
#define ETn  128
#define Hn   128
#define G3n  384
#define NDEG 12

typedef __attribute__((ext_vector_type(2))) float f32x2;
typedef __attribute__((ext_vector_type(2))) _Float16 f16x2;
typedef __attribute__((ext_vector_type(8))) _Float16 f16x8;
typedef __attribute__((ext_vector_type(4))) float f32x4;

// DPP helpers (VALU cross-lane, no LDS pipe)
#define DPPF(x, ctrl) __int_as_float(__builtin_amdgcn_update_dpp(0, __float_as_int(x), (ctrl), 0xF, 0xF, true))
#define QP_XOR1 0xB1   // quad_perm [1,0,3,2]
#define QP_XOR2 0x4E   // quad_perm [2,3,0,1]
#define QP_B0   0x00
#define QP_B1   0x55
#define QP_B2   0xAA
#define QP_B3   0xFF

// odd sin polynomial, |x| <= ~0.5, err < 5e-9
__device__ __forceinline__ float sin_poly(float x) {
    const float x2 = x * x;
    float r = -1.9841270114e-04f;
    r = fmaf(r, x2,  8.3333337680e-03f);
    r = fmaf(r, x2, -1.6666667163e-01f);
    return fmaf(r * x2, x, x);
}
// even cos polynomial, |x| <= ~0.5, err < 3e-10
__device__ __forceinline__ float cos_poly(float x) {
    const float x2 = x * x;
    float r =  2.4801587642e-05f;
    r = fmaf(r, x2, -1.3888888899e-03f);
    r = fmaf(r, x2,  4.1666667908e-02f);
    r = fmaf(r, x2, -5.0000000000e-01f);
    return fmaf(r, x2, 1.0f);
}

// ---- workspace layout (float offsets) ----
#define WS_C    0                          // 128*12
#define WS_WT   4096                       // 768*32
#define WS_B2   (WS_WT + 768*32)           // 768 (pad 1024)
#define WS_CLS  (WS_B2 + 1024)             // 64*256 (clsin; dead during attn -> reuse head for sP)
#define WS_G0   (WS_CLS + Bn*2*Hn)         // region of 2097152 floats (transient aliases)
#define WS_GI   (WS_G0 + Bn*LQn*2*Hn)      // 8192*768
// aliases inside WS_G0 region:
//   phase 1 (attn -> gemm_att): accP = 8 slices x 8192 x 32 = 2097152 floats (exact fit)
//   phase 2 (gru0 -> gemm16):   g0f16 (half*) [0, 524288 floats), w16 (half*) at +1100000
#define WS_ACCP WS_G0
#define WS_SP   WS_CLS                     // sP[8192] aliases clsin head (disjoint lifetime)
#define WS_W16  (WS_G0 + 1100000)

// =================== K1: merged score-polynomial coefficients ===================
__global__ __launch_bounds__(128) void k_coef(
    const float* __restrict__ qtimes, const float* __restrict__ lin_w,
    const float* __restrict__ lin_b, const float* __restrict__ per_w,
    const float* __restrict__ per_b, const float* __restrict__ wq,
    const float* __restrict__ bq, const float* __restrict__ wk,
    const float* __restrict__ bk, float* __restrict__ C)
{
    __shared__ float qe[ETn], qp_l[ETn], qt_l[ETn], bas[NDEG * 128], red[96], qbk_red[32];
    const int q = blockIdx.x, tid = threadIdx.x;
    if (tid < ETn - 1) {
        const float w = per_w[tid], bb = per_b[tid];
        const float sb = sin_poly(bb), cb = cos_poly(bb);
        float wp = 1.f;
#pragma unroll
        for (int d = 0; d < NDEG; ++d) {
            const float sd = ((d & 3) == 0) ? sb : ((d & 3) == 1) ? cb : ((d & 3) == 2) ? -sb : -cb;
            bas[d * 128 + tid] = wp * sd;
            wp *= w / (float)(d + 1);
        }
    }
    const float t = qtimes[q];
    qe[tid] = (tid == 0) ? fmaf(t, lin_w[0], lin_b[0])
                         : sin_poly(fmaf(t, per_w[tid - 1], per_b[tid - 1]));
    __syncthreads();
    {
        float a = bq[tid];
#pragma unroll 16
        for (int i = 0; i < ETn; ++i) a = fmaf(qe[i], wq[i * ETn + tid], a);
        qp_l[tid] = a;
    }
    __syncthreads();
    {
        const float4* wk4 = (const float4*)(wk + (size_t)tid * ETn);
        const float4* qp4 = (const float4*)qp_l;
        float a = 0.f;
#pragma unroll
        for (int k = 0; k < 32; ++k) {
            const float4 w4 = wk4[k], p4 = qp4[k];
            a += w4.x * p4.x + w4.y * p4.y + w4.z * p4.z + w4.w * p4.w;
        }
        qt_l[tid] = a;
    }
    __syncthreads();
    if (tid < 96) {
        const int d = tid >> 3, g = tid & 7;
        float p = 0.f;
        for (int j = g; j < ETn - 1; j += 8) p = fmaf(qt_l[j + 1], bas[d * 128 + j], p);
        red[tid] = p;
    } else {
        const int g2 = tid - 96;
        float p = 0.f;
#pragma unroll
        for (int k = 0; k < 4; ++k) p = fmaf(qp_l[g2 + 32 * k], bk[g2 + 32 * k], p);
        qbk_red[g2] = p;
    }
    __syncthreads();
    if (tid < NDEG) {
        const int d = tid;
        float s = red[d * 8 + 0] + red[d * 8 + 1] + red[d * 8 + 2] + red[d * 8 + 3]
                + red[d * 8 + 4] + red[d * 8 + 5] + red[d * 8 + 6] + red[d * 8 + 7];
        if (d == 0) {
            float qbk = 0.f;
#pragma unroll
            for (int k = 0; k < 32; ++k) qbk += qbk_red[k];
            s += qt_l[0] * lin_b[0] + qbk;
        }
        if (d == 1) s += qt_l[0] * lin_w[0];
        C[q * NDEG + d] = s * 0.08838834764831845f;   // 1/sqrt(128)
    }
}

// =================== K1d: fold wo (+bo) into layer-0 wih + zero sP ===================
__global__ __launch_bounds__(256) void k_fuse(
    const float* __restrict__ wih, const float* __restrict__ wo,
    const float* __restrict__ bo, const float* __restrict__ bih,
    float* __restrict__ Wt, float* __restrict__ bias2, float* __restrict__ sP)
{
    const int t = blockIdx.x * 256 + threadIdx.x;
    if (t < 768 * 32) {
        const int o = t >> 5, d = t & 31;
        const float4* wr4 = (const float4*)(wih + (size_t)o * 128);
        const float4* wc4 = (const float4*)(wo + (size_t)d * 128);
        float a = 0.f;
#pragma unroll
        for (int k = 0; k < 32; ++k) {
            const float4 r4 = wr4[k], c4 = wc4[k];
            a += r4.x * c4.x + r4.y * c4.y + r4.z * c4.z + r4.w * c4.w;
        }
        Wt[t] = a;
    } else if (t < 768 * 33) {
        const int o = t - 768 * 32;
        const float4* wr4 = (const float4*)(wih + (size_t)o * 128);
        const float4* bo4 = (const float4*)bo;
        float a = bih[o];
#pragma unroll
        for (int k = 0; k < 32; ++k) {
            const float4 r4 = wr4[k], b4 = bo4[k];
            a += r4.x * b4.x + r4.y * b4.y + r4.z * b4.z + r4.w * b4.w;
        }
        bias2[o] = a;
    } else if (t < 768 * 33 + Bn * LQn) {
        sP[t - 768 * 33] = 0.f;           // zero the atomic softmax-denominator buffer
    }
}

// =================== K1e: pack layer-1 wih to f16 (768 x 256) ===================
__global__ __launch_bounds__(256) void k_w16(
    const float* __restrict__ w, _Float16* __restrict__ w16)
{
    const int idx = blockIdx.x * 256 + threadIdx.x;
    if (idx < 768 * 256) w16[idx] = (_Float16)w[idx];
}

// =================== K2: attention — 8-way l-split (2 blocks/CU, 4 waves/SIMD) ===================
__global__ __launch_bounds__(512, 4) void k_attn(
    const float* __restrict__ x, const float* __restrict__ tsteps,
    const float* __restrict__ Cc, float* __restrict__ accP, float* __restrict__ sP)
{
    __shared__ __align__(16) char smem[4 * 128 * 36 * 4];   // 73728 B (xls/slab union)
    float4* xls  = (float4*)smem;
    float*  slabf = (float*)smem;
#define SLAB(s, qq, c) slabf[(((s) * 128) + (qq)) * 36 + (c)]
    const int tid = threadIdx.x;
    const int b = blockIdx.x >> 3, lsplit = blockIdx.x & 7;
    const int i = tid & 3, qt = (tid >> 2) & 31, ls2 = tid >> 7;
    const int qown = 4 * qt + i;
    const int u = tid & 127;

    float c[NDEG];
#pragma unroll
    for (int d = 0; d < NDEG; ++d) c[d] = Cc[qown * NDEG + d];

    const int l0 = lsplit * 512 + ls2 * 128;
    const float4* tg4 = (const float4*)(tsteps + (size_t)b * Ln + l0);
    const float4* xg  = (const float4*)(x + ((size_t)b * Ln + l0) * Dn);

    f32x2 acc2[4][4];
#pragma unroll
    for (int m = 0; m < 4; ++m)
#pragma unroll
        for (int e = 0; e < 4; ++e) { acc2[m][e].x = 0.f; acc2[m][e].y = 0.f; }
    float s_own = 0.f;

    float4 xr[4];
#pragma unroll
    for (int w = 0; w < 4; ++w) xr[w] = xg[u + 128 * w];

    for (int ch = 0; ch < 2; ++ch) {
        __syncthreads();
#pragma unroll
        for (int w = 0; w < 4; ++w) xls[ls2 * 512 + u + 128 * w] = xr[w];
        __syncthreads();
        if (ch < 1) {
            const int off = 512;
#pragma unroll
            for (int w = 0; w < 4; ++w) xr[w] = xg[off + u + 128 * w];
        }
        const float4* xrow = &xls[ls2 * 512];
        for (int k = 0; k < 16; ++k) {
            const float4 t4 = tg4[ch * 16 + k];
#pragma unroll
            for (int jj = 0; jj < 4; ++jj) {
                const float t = (jj == 0) ? t4.x : (jj == 1) ? t4.y : (jj == 2) ? t4.z : t4.w;
                float sc = c[NDEG - 1];
#pragma unroll
                for (int d = NDEG - 2; d >= 0; --d) sc = fmaf(sc, t, c[d]);
                const float pe = __expf(sc);
                s_own += pe;
                const float p0 = DPPF(pe, QP_B0);
                const float p1 = DPPF(pe, QP_B1);
                const float p2 = DPPF(pe, QP_B2);
                const float p3 = DPPF(pe, QP_B3);
                const int lrow = (k * 4 + jj) * 8;
                const float4 xa = xrow[lrow + 2 * i];
                const float4 xb = xrow[lrow + 2 * i + 1];
                f32x2 xa0; xa0.x = xa.x; xa0.y = xa.y;
                f32x2 xa1; xa1.x = xa.z; xa1.y = xa.w;
                f32x2 xb0; xb0.x = xb.x; xb0.y = xb.y;
                f32x2 xb1; xb1.x = xb.z; xb1.y = xb.w;
#define PKA(m, pv) { f32x2 pp; pp.x = (pv); pp.y = (pv); \
    acc2[m][0] = __builtin_elementwise_fma(pp, xa0, acc2[m][0]); \
    acc2[m][1] = __builtin_elementwise_fma(pp, xa1, acc2[m][1]); \
    acc2[m][2] = __builtin_elementwise_fma(pp, xb0, acc2[m][2]); \
    acc2[m][3] = __builtin_elementwise_fma(pp, xb1, acc2[m][3]); }
                PKA(0, p0) PKA(1, p1) PKA(2, p2) PKA(3, p3)
#undef PKA
            }
        }
    }
    __syncthreads();   // all xls reads complete; smem region reused as slab
#pragma unroll
    for (int m = 0; m < 4; ++m) {
        float4 f4a, f4b;
        f4a.x = acc2[m][0].x; f4a.y = acc2[m][0].y; f4a.z = acc2[m][1].x; f4a.w = acc2[m][1].y;
        f4b.x = acc2[m][2].x; f4b.y = acc2[m][2].y; f4b.z = acc2[m][3].x; f4b.w = acc2[m][3].y;
        *(float4*)&SLAB(ls2, 4 * qt + m, 8 * i)     = f4a;
        *(float4*)&SLAB(ls2, 4 * qt + m, 8 * i + 4) = f4b;
    }
    SLAB(ls2, qown, 32) = s_own;
    __syncthreads();
    const int q = tid & 127, part = tid >> 7;
#pragma unroll
    for (int j = 0; j < 2; ++j) {
        const int off = (part * 2 + j) * 4;
        float4 r  = *(float4*)&SLAB(0, q, off);
        float4 r1 = *(float4*)&SLAB(1, q, off);
        float4 r2 = *(float4*)&SLAB(2, q, off);
        float4 r3 = *(float4*)&SLAB(3, q, off);
        r.x += r1.x + r2.x + r3.x; r.y += r1.y + r2.y + r3.y;
        r.z += r1.z + r2.z + r3.z; r.w += r1.w + r2.w + r3.w;
        *(float4*)&accP[((((size_t)lsplit * Bn + b) * LQn + q) * 32) + off] = r;
    }
    if (part == 0) {
        atomicAdd(&sP[(size_t)b * LQn + q],
                  SLAB(0, q, 32) + SLAB(1, q, 32) + SLAB(2, q, 32) + SLAB(3, q, 32));
    }
#undef SLAB
}

// =================== K3a: GEMM layer-0: A = (sum_8 accP)/sP, K=32, pk core ===================
__global__ __launch_bounds__(256) void k_gemm_att(
    const float* __restrict__ accP, const float* __restrict__ sP,
    const float* __restrict__ Bm, const float* __restrict__ bias,
    float* __restrict__ Cm)
{
    __shared__ float4 A_l[64 * 8];
    __shared__ float4 B_l[64 * 8];
    const int tid = threadIdx.x;
    const int m0 = blockIdx.x * 64, n0 = blockIdx.y * 64;
    const int r0 = (tid >> 4) << 2, c0 = (tid & 15) << 2;
    f32x2 acc2[4][4];
#pragma unroll
    for (int a = 0; a < 4; ++a)
#pragma unroll
        for (int bb = 0; bb < 4; ++bb) { acc2[a][bb].x = 0.f; acc2[a][bb].y = 0.f; }
    const float4* Ag = (const float4*)accP;
    const float4* Bg = (const float4*)Bm;

#pragma unroll
    for (int w = 0; w < 2; ++w) {
        const int idx = tid + w * 256;
        const int row = idx >> 3, c4 = idx & 7;
        const int sc = (c4 + row + (row >> 2)) & 7;
        const int m = m0 + row;
        float4 av = Ag[(size_t)m * 8 + c4];
#pragma unroll
        for (int s = 1; s < 8; ++s) {
            const float4 as = Ag[((size_t)s * 8192 + m) * 8 + c4];
            av.x += as.x; av.y += as.y; av.z += as.z; av.w += as.w;
        }
        const float inv = 1.f / sP[m];
        av.x *= inv; av.y *= inv; av.z *= inv; av.w *= inv;
        A_l[row * 8 + sc] = av;
        B_l[row * 8 + sc] = Bg[(size_t)(n0 + row) * 8 + c4];
    }
    __syncthreads();
#pragma unroll
    for (int k4 = 0; k4 < 8; ++k4) {
        float4 av[4], bv[4];
#pragma unroll
        for (int j = 0; j < 4; ++j) {
            const int ra = r0 + j;
            av[j] = A_l[ra * 8 + ((k4 + ra + (ra >> 2)) & 7)];
        }
#pragma unroll
        for (int j = 0; j < 4; ++j) {
            const int rb = c0 + j;
            bv[j] = B_l[rb * 8 + ((k4 + rb + (rb >> 2)) & 7)];
        }
#pragma unroll
        for (int ri = 0; ri < 4; ++ri) {
            f32x2 alo; alo.x = av[ri].x; alo.y = av[ri].y;
            f32x2 ahi; ahi.x = av[ri].z; ahi.y = av[ri].w;
#pragma unroll
            for (int ci = 0; ci < 4; ++ci) {
                f32x2 blo; blo.x = bv[ci].x; blo.y = bv[ci].y;
                f32x2 bhi; bhi.x = bv[ci].z; bhi.y = bv[ci].w;
                acc2[ri][ci] = __builtin_elementwise_fma(alo, blo, acc2[ri][ci]);
                acc2[ri][ci] = __builtin_elementwise_fma(ahi, bhi, acc2[ri][ci]);
            }
        }
    }
#pragma unroll
    for (int ri = 0; ri < 4; ++ri) {
        float4 o4;
        o4.x = acc2[ri][0].x + acc2[ri][0].y + bias[n0 + c0 + 0];
        o4.y = acc2[ri][1].x + acc2[ri][1].y + bias[n0 + c0 + 1];
        o4.z = acc2[ri][2].x + acc2[ri][2].y + bias[n0 + c0 + 2];
        o4.w = acc2[ri][3].x + acc2[ri][3].y + bias[n0 + c0 + 3];
        *(float4*)&Cm[(size_t)(m0 + r0 + ri) * 768 + n0 + c0] = o4;
    }
}

// =================== K3b: layer-1 GEMM via MFMA f16 (verified R16) ===================
__global__ __launch_bounds__(256) void k_gemm16(
    const _Float16* __restrict__ g0, const _Float16* __restrict__ w16,
    const float* __restrict__ bias, float* __restrict__ Cm)
{
    const int tid = threadIdx.x;
    const int wave = tid >> 6, lane = tid & 63;
    const int m0 = blockIdx.x * 64 + wave * 16;
    const int n0 = blockIdx.y * 64;
    const int koff = 8 * (lane >> 4);

    const _Float16* Ab  = g0 + (size_t)(m0 + (lane & 15)) * 256 + koff;
    const _Float16* Bb0 = w16 + (size_t)(n0 +  0 + (lane & 15)) * 256 + koff;
    const _Float16* Bb1 = w16 + (size_t)(n0 + 16 + (lane & 15)) * 256 + koff;
    const _Float16* Bb2 = w16 + (size_t)(n0 + 32 + (lane & 15)) * 256 + koff;
    const _Float16* Bb3 = w16 + (size_t)(n0 + 48 + (lane & 15)) * 256 + koff;

    f32x4 acc0 = {0.f, 0.f, 0.f, 0.f}, acc1 = acc0, acc2 = acc0, acc3 = acc0;
#pragma unroll
    for (int k0 = 0; k0 < 256; k0 += 32) {
        const f16x8 a  = *(const f16x8*)(Ab  + k0);
        const f16x8 b0 = *(const f16x8*)(Bb0 + k0);
        const f16x8 b1 = *(const f16x8*)(Bb1 + k0);
        const f16x8 b2 = *(const f16x8*)(Bb2 + k0);
        const f16x8 b3 = *(const f16x8*)(Bb3 + k0);
        acc0 = __builtin_amdgcn_mfma_f32_16x16x32_f16(a, b0, acc0, 0, 0, 0);
        acc1 = __builtin_amdgcn_mfma_f32_16x16x32_f16(a, b1, acc1, 0, 0, 0);
        acc2 = __builtin_amdgcn_mfma_f32_16x16x32_f16(a, b2, acc2, 0, 0, 0);
        acc3 = __builtin_amdgcn_mfma_f32_16x16x32_f16(a, b3, acc3, 0, 0, 0);
    }
    const int mr = m0 + (lane >> 4) * 4;
    const int nc = lane & 15;
#pragma unroll
    for (int r = 0; r < 4; ++r) {
        Cm[(size_t)(mr + r) * 768 + n0 +  0 + nc] = acc0[r] + bias[n0 +  0 + nc];
        Cm[(size_t)(mr + r) * 768 + n0 + 16 + nc] = acc1[r] + bias[n0 + 16 + nc];
        Cm[(size_t)(mr + r) * 768 + n0 + 32 + nc] = acc2[r] + bias[n0 + 32 + nc];
        Cm[(size_t)(mr + r) * 768 + n0 + 48 + nc] = acc3[r] + bias[n0 + 48 + nc];
    }
}

// =================== K4: GRU — 2 direction-chains per block (2 waves/SIMD TLP) ===================
// 512 threads = {dir = tid>>8, t8 = tid&255}; per-thread work IDENTICAL to R19's proven
// gstep (j = t8>>1, q = t8&1, 64-wide f16 slices, 48 weight VGPRs, demand ~80).
// amdgpu_waves_per_eu(2,2): R7 measured this grants ~88 VGPRs at 512 thr — 80 fits.
// Waves 0-3 (dir0) and 4-7 (dir1) interleave on the same SIMDs: independent chains
// hide each other's LDS/exp/barrier stalls. Grid 64 = (b).
__global__ __launch_bounds__(512) __attribute__((amdgpu_waves_per_eu(2, 2)))
void k_gru(
    const float* __restrict__ gi, const float* __restrict__ whh,
    const float* __restrict__ bhh, _Float16* __restrict__ seq_out,
    float* __restrict__ final_out)
{
    __shared__ _Float16 h16[2][2][Hn];    // [buf][dir][j]
    __shared__ float    h32[2][2][Hn];
    const int tid = threadIdx.x;
    const int b = blockIdx.x;
    const int dir = tid >> 8;             // waves 0-3: dir0, waves 4-7: dir1
    const int t8 = tid & 255;
    const int j = t8 >> 1, q = t8 & 1;

    f16x2 wr[32], wz[32], wn[32];
    {
        const float* wb = whh + ((size_t)dir * G3n + j) * Hn + 64 * q;
        const f32x2* p0 = (const f32x2*)(wb);
        const f32x2* p1 = (const f32x2*)(wb + (size_t)128 * Hn);
        const f32x2* p2 = (const f32x2*)(wb + (size_t)256 * Hn);
#pragma unroll
        for (int k = 0; k < 32; ++k) {
            f32x2 a = p0[k], z2 = p1[k], c2 = p2[k];
            wr[k].x = (_Float16)a.x;  wr[k].y = (_Float16)a.y;
            wz[k].x = (_Float16)z2.x; wz[k].y = (_Float16)z2.y;
            wn[k].x = (_Float16)c2.x; wn[k].y = (_Float16)c2.y;
        }
    }
#pragma unroll
    for (int k = 0; k < 32; ++k) {
        asm volatile("" : "+v"(wr[k]));
        asm volatile("" : "+v"(wz[k]));
        asm volatile("" : "+v"(wn[k]));
    }
    const float bhr = bhh[dir * G3n + j];
    const float bhz = bhh[dir * G3n + 128 + j];
    const float bhn = bhh[dir * G3n + 256 + j];

    // init: 2 bufs x 2 dirs x 128 = 512 entries; one per thread
    ((float*)h32)[tid] = 0.f;
    ((_Float16*)h16)[tid] = (_Float16)0.f;
    __syncthreads();

    const long sstride = dir ? -768 : 768;
    const float* gptr = gi + (size_t)b * LQn * 768 + dir * G3n + j
                        + (size_t)(dir ? LQn - 1 : 0) * 768;

    int cur = 0;
    float hlast = 0.f;

    auto gstep = [&](const float gir, const float giz, const float gin, const int step) {
        const float hold = h32[cur][dir][j];
        const float4* hb4 = (const float4*)(&h16[cur][dir][64 * q]);
        float srA = 0.f, szA = 0.f, snA = 0.f;
        float srB = 0.f, szB = 0.f, snB = 0.f;
#pragma unroll
        for (int k2 = 0; k2 < 4; ++k2) {
            float4 hv = hb4[k2];
            f16x2 h0 = *(f16x2*)&hv.x;
            f16x2 h1 = *(f16x2*)&hv.y;
            f16x2 h2 = *(f16x2*)&hv.z;
            f16x2 h3 = *(f16x2*)&hv.w;
            asm("v_dot2_f32_f16 %0, %1, %2, %0" : "+v"(srA) : "v"(wr[4 * k2 + 0]), "v"(h0));
            asm("v_dot2_f32_f16 %0, %1, %2, %0" : "+v"(szA) : "v"(wz[4 * k2 + 0]), "v"(h0));
            asm("v_dot2_f32_f16 %0, %1, %2, %0" : "+v"(snA) : "v"(wn[4 * k2 + 0]), "v"(h0));
            asm("v_dot2_f32_f16 %0, %1, %2, %0" : "+v"(srA) : "v"(wr[4 * k2 + 1]), "v"(h1));
            asm("v_dot2_f32_f16 %0, %1, %2, %0" : "+v"(szA) : "v"(wz[4 * k2 + 1]), "v"(h1));
            asm("v_dot2_f32_f16 %0, %1, %2, %0" : "+v"(snA) : "v"(wn[4 * k2 + 1]), "v"(h1));
            asm("v_dot2_f32_f16 %0, %1, %2, %0" : "+v"(srA) : "v"(wr[4 * k2 + 2]), "v"(h2));
            asm("v_dot2_f32_f16 %0, %1, %2, %0" : "+v"(szA) : "v"(wz[4 * k2 + 2]), "v"(h2));
            asm("v_dot2_f32_f16 %0, %1, %2, %0" : "+v"(snA) : "v"(wn[4 * k2 + 2]), "v"(h2));
            asm("v_dot2_f32_f16 %0, %1, %2, %0" : "+v"(srA) : "v"(wr[4 * k2 + 3]), "v"(h3));
            asm("v_dot2_f32_f16 %0, %1, %2, %0" : "+v"(szA) : "v"(wz[4 * k2 + 3]), "v"(h3));
            asm("v_dot2_f32_f16 %0, %1, %2, %0" : "+v"(snA) : "v"(wn[4 * k2 + 3]), "v"(h3));
        }
#pragma unroll
        for (int k2 = 4; k2 < 8; ++k2) {
            float4 hv = hb4[k2];
            f16x2 h0 = *(f16x2*)&hv.x;
            f16x2 h1 = *(f16x2*)&hv.y;
            f16x2 h2 = *(f16x2*)&hv.z;
            f16x2 h3 = *(f16x2*)&hv.w;
            asm("v_dot2_f32_f16 %0, %1, %2, %0" : "+v"(srB) : "v"(wr[4 * k2 + 0]), "v"(h0));
            asm("v_dot2_f32_f16 %0, %1, %2, %0" : "+v"(szB) : "v"(wz[4 * k2 + 0]), "v"(h0));
            asm("v_dot2_f32_f16 %0, %1, %2, %0" : "+v"(snB) : "v"(wn[4 * k2 + 0]), "v"(h0));
            asm("v_dot2_f32_f16 %0, %1, %2, %0" : "+v"(srB) : "v"(wr[4 * k2 + 1]), "v"(h1));
            asm("v_dot2_f32_f16 %0, %1, %2, %0" : "+v"(szB) : "v"(wz[4 * k2 + 1]), "v"(h1));
            asm("v_dot2_f32_f16 %0, %1, %2, %0" : "+v"(snB) : "v"(wn[4 * k2 + 1]), "v"(h1));
            asm("v_dot2_f32_f16 %0, %1, %2, %0" : "+v"(srB) : "v"(wr[4 * k2 + 2]), "v"(h2));
            asm("v_dot2_f32_f16 %0, %1, %2, %0" : "+v"(szB) : "v"(wz[4 * k2 + 2]), "v"(h2));
            asm("v_dot2_f32_f16 %0, %1, %2, %0" : "+v"(snB) : "v"(wn[4 * k2 + 2]), "v"(h2));
            asm("v_dot2_f32_f16 %0, %1, %2, %0" : "+v"(srB) : "v"(wr[4 * k2 + 3]), "v"(h3));
            asm("v_dot2_f32_f16 %0, %1, %2, %0" : "+v"(szB) : "v"(wz[4 * k2 + 3]), "v"(h3));
            asm("v_dot2_f32_f16 %0, %1, %2, %0" : "+v"(snB) : "v"(wn[4 * k2 + 3]), "v"(h3));
        }
        float sr = srA + srB, sz = szA + szB, sn = snA + snB;
        sr += DPPF(sr, QP_XOR1);
        sz += DPPF(sz, QP_XOR1);
        sn += DPPF(sn, QP_XOR1);
        const float r = 1.f / (1.f + __expf(-(gir + sr + bhr)));
        const float z = 1.f / (1.f + __expf(-(giz + sz + bhz)));
        const float nx = gin + r * (sn + bhn);
        const float n = 1.f - 2.f / (1.f + __expf(2.f * nx));   // tanh
        const float hn = n + z * (hold - n);
        if (q == 0) {
            h32[cur ^ 1][dir][j] = hn;
            h16[cur ^ 1][dir][j] = (_Float16)hn;
            if (seq_out) {
                const int l = dir ? (LQn - 1 - step) : step;
                seq_out[((size_t)(b * LQn + l)) * (2 * Hn) + dir * Hn + j] = (_Float16)hn;
            }
        }
        hlast = hn;
        cur ^= 1;
        // LDS-only barrier: do NOT drain vmcnt (gi prefetch + seq stores stay in flight)
        asm volatile("s_waitcnt lgkmcnt(0)\n\ts_barrier" ::: "memory");
    };

    float gA[3], gB[3];
#define GLD(dst, s) { const long o = (long)(s) * sstride; \
    dst[0] = gptr[o]; dst[1] = gptr[o + 128]; dst[2] = gptr[o + 256]; }
    GLD(gA, 0) GLD(gB, 1)
    for (int s0 = 0; s0 < LQn; s0 += 2) {
        gstep(gA[0], gA[1], gA[2], s0);
        { const int sn2 = (s0 + 2 < LQn) ? s0 + 2 : LQn - 1; GLD(gA, sn2) }
        gstep(gB[0], gB[1], gB[2], s0 + 1);
        { const int sn2 = (s0 + 3 < LQn) ? s0 + 3 : LQn - 1; GLD(gB, sn2) }
    }
#undef GLD
    if (final_out && q == 0) final_out[b * 2 * Hn + dir * Hn + j] = hlast;
}

// =================== K5: classifier MLP ===================
__global__ __launch_bounds__(256) void k_cls(
    const float* __restrict__ cls_in,
    const float* __restrict__ c1w, const float* __restrict__ c1b,
    const float* __restrict__ c2w, const float* __restrict__ c2b,
    const float* __restrict__ c3w, const float* __restrict__ c3b,
    float* __restrict__ out)
{
    __shared__ float ci[256], y1[128], y2[64];
    const int b = blockIdx.x, tid = threadIdx.x;
    ci[tid] = cls_in[b * 256 + tid];
    __syncthreads();
    if (tid < 128) { float a = c1b[tid]; for (int i = 0; i < 256; ++i) a += ci[i] * c1w[i * 128 + tid]; y1[tid] = a; }
    __syncthreads();
    if (tid < 64)  { float a = c2b[tid]; for (int i = 0; i < 128; ++i) a += y1[i] * c2w[i * 64 + tid];  y2[tid] = a; }
    __syncthreads();
    if (tid < 6)   { float a = c3b[tid]; for (int i = 0; i < 64; ++i)  a += y2[i] * c3w[i * 6 + tid];   out[b * 6 + tid] = a; }
}

// =================== launch ===================
extern "C" void kernel_launch(void* const* d_in, const int* in_sizes, int n_in,
                              void* d_out, int out_size, void* d_ws, size_t ws_size,
                              hipStream_t stream)
{
    const float* x        = (const float*)d_in[0];
    const float* tsteps   = (const float*)d_in[1];
    const float* qtimes   = (const float*)d_in[2];
    const float* lin_w    = (const float*)d_in[3];
    const float* lin_b    = (const float*)d_in[4];
    const float* per_w    = (const float*)d_in[5];
    const float* per_b    = (const float*)d_in[6];
    const float* wq       = (const float*)d_in[7];
    const float* bq       = (const float*)d_in[8];
    const float* wk       = (const float*)d_in[9];
    const float* bk       = (const float*)d_in[10];
    const float* wo       = (const float*)d_in[11];
    const float* bo       = (const float*)d_in[12];
    const float* g0_wih   = (const float*)d_in[13];
    const float* g0_whh   = (const float*)d_in[14];
    const float* g0_bih   = (const float*)d_in[15];
    const float* g0_bhh   = (const float*)d_in[16];
    const float* g1_wih   = (const float*)d_in[17];
    const float* g1_whh   = (const float*)d_in[18];
    const float* g1_bih   = (const float*)d_in[19];
    const float* g1_bhh   = (const float*)d_in[20];
    const float* c1w      = (const float*)d_in[21];
    const float* c1b      = (const float*)d_in[22];
    const float* c2w      = (const float*)d_in[23];
    const float* c2b      = (const float*)d_in[24];
    const float* c3w      = (const float*)d_in[25];
    const float* c3b      = (const float*)d_in[26];
    float* out = (float*)d_out;
    float* ws  = (float*)d_ws;

    float* Cws   = ws + WS_C;
    float* Wt    = ws + WS_WT;
    float* bias2 = ws + WS_B2;
    float* clsin = ws + WS_CLS;
    float* accP  = ws + WS_ACCP;
    float* sPb   = ws + WS_SP;                     // 8192 floats, aliases clsin head (disjoint lifetime)
    float* gibuf = ws + WS_GI;
    _Float16* g0f16 = (_Float16*)(ws + WS_G0);     // after accP dead
    _Float16* w16b  = (_Float16*)(ws + WS_W16);    // after accP dead

    k_coef<<<128, 128, 0, stream>>>(qtimes, lin_w, lin_b, per_w, per_b, wq, bq, wk, bk, Cws);
    k_fuse<<<131, 256, 0, stream>>>(g0_wih, wo, bo, g0_bih, Wt, bias2, sPb);
    k_attn<<<512, 512, 0, stream>>>(x, tsteps, Cws, accP, sPb);

    // layer 0: gi = att @ Wt^T + bias2 (att assembled in-GEMM from 8-slice accP / atomic sP)
    k_gemm_att<<<dim3(128, 12), 256, 0, stream>>>(accP, sPb, Wt, bias2, gibuf);
    // pack layer-1 weights to f16 (accP now dead; overlaps gru0)
    k_w16<<<768, 256, 0, stream>>>(g1_wih, w16b);
    k_gru<<<64, 512, 0, stream>>>(gibuf, g0_whh, g0_bhh, g0f16, nullptr);

    // layer 1: gi = g0f16 @ w16^T + bih  (MFMA f16)
    k_gemm16<<<dim3(128, 12), 256, 0, stream>>>(g0f16, w16b, g1_bih, gibuf);
    k_gru<<<64, 512, 0, stream>>>(gibuf, g1_whh, g1_bhh, nullptr, clsin);

    k_cls<<<64, 256, 0, stream>>>(clsin, c1w, c1b, c2w, c2b, c3w, c3b, out);
}

// Round 21
// 270.646 us; speedup vs baseline: 1.2891x; 1.2891x over previous
//
#include <hip/hip_runtime.h>
#include <math.h>

#define Bn   64
#define Ln   4096
#define LQn  128
#define Dn   32
#define ETn  128
#define Hn   128
#define G3n  384
#define NDEG 12

typedef __attribute__((ext_vector_type(2))) float f32x2;
typedef __attribute__((ext_vector_type(2))) _Float16 f16x2;
typedef __attribute__((ext_vector_type(8))) _Float16 f16x8;
typedef __attribute__((ext_vector_type(4))) float f32x4;

// DPP helpers (VALU cross-lane, no LDS pipe)
#define DPPF(x, ctrl) __int_as_float(__builtin_amdgcn_update_dpp(0, __float_as_int(x), (ctrl), 0xF, 0xF, true))
#define QP_XOR1 0xB1   // quad_perm [1,0,3,2]
#define QP_XOR2 0x4E   // quad_perm [2,3,0,1]
#define QP_B0   0x00
#define QP_B1   0x55
#define QP_B2   0xAA
#define QP_B3   0xFF

// odd sin polynomial, |x| <= ~0.5, err < 5e-9
__device__ __forceinline__ float sin_poly(float x) {
    const float x2 = x * x;
    float r = -1.9841270114e-04f;
    r = fmaf(r, x2,  8.3333337680e-03f);
    r = fmaf(r, x2, -1.6666667163e-01f);
    return fmaf(r * x2, x, x);
}
// even cos polynomial, |x| <= ~0.5, err < 3e-10
__device__ __forceinline__ float cos_poly(float x) {
    const float x2 = x * x;
    float r =  2.4801587642e-05f;
    r = fmaf(r, x2, -1.3888888899e-03f);
    r = fmaf(r, x2,  4.1666667908e-02f);
    r = fmaf(r, x2, -5.0000000000e-01f);
    return fmaf(r, x2, 1.0f);
}

// ---- workspace layout (float offsets) ----
#define WS_C    0                          // 128*12
#define WS_WT   4096                       // 768*32
#define WS_B2   (WS_WT + 768*32)           // 768 (pad 1024)
#define WS_CLS  (WS_B2 + 1024)             // 64*256 (clsin; dead during attn -> reuse head for sP)
#define WS_G0   (WS_CLS + Bn*2*Hn)         // region of 2097152 floats (transient aliases)
#define WS_GI   (WS_G0 + Bn*LQn*2*Hn)      // 8192*768
// aliases inside WS_G0 region:
//   phase 1 (attn -> gemm_att): accP = 8 slices x 8192 x 32 = 2097152 floats (exact fit)
//   phase 2 (gru0 -> gemm16):   g0f16 (half*) [0, 524288 floats), w16 (half*) at +1100000
#define WS_ACCP WS_G0
#define WS_SP   WS_CLS                     // sP[8192] aliases clsin head (disjoint lifetime)
#define WS_W16  (WS_G0 + 1100000)

// =================== K1: merged score-polynomial coefficients ===================
__global__ __launch_bounds__(128) void k_coef(
    const float* __restrict__ qtimes, const float* __restrict__ lin_w,
    const float* __restrict__ lin_b, const float* __restrict__ per_w,
    const float* __restrict__ per_b, const float* __restrict__ wq,
    const float* __restrict__ bq, const float* __restrict__ wk,
    const float* __restrict__ bk, float* __restrict__ C)
{
    __shared__ float qe[ETn], qp_l[ETn], qt_l[ETn], bas[NDEG * 128], red[96], qbk_red[32];
    const int q = blockIdx.x, tid = threadIdx.x;
    if (tid < ETn - 1) {
        const float w = per_w[tid], bb = per_b[tid];
        const float sb = sin_poly(bb), cb = cos_poly(bb);
        float wp = 1.f;
#pragma unroll
        for (int d = 0; d < NDEG; ++d) {
            const float sd = ((d & 3) == 0) ? sb : ((d & 3) == 1) ? cb : ((d & 3) == 2) ? -sb : -cb;
            bas[d * 128 + tid] = wp * sd;
            wp *= w / (float)(d + 1);
        }
    }
    const float t = qtimes[q];
    qe[tid] = (tid == 0) ? fmaf(t, lin_w[0], lin_b[0])
                         : sin_poly(fmaf(t, per_w[tid - 1], per_b[tid - 1]));
    __syncthreads();
    {
        float a = bq[tid];
#pragma unroll 16
        for (int i = 0; i < ETn; ++i) a = fmaf(qe[i], wq[i * ETn + tid], a);
        qp_l[tid] = a;
    }
    __syncthreads();
    {
        const float4* wk4 = (const float4*)(wk + (size_t)tid * ETn);
        const float4* qp4 = (const float4*)qp_l;
        float a = 0.f;
#pragma unroll
        for (int k = 0; k < 32; ++k) {
            const float4 w4 = wk4[k], p4 = qp4[k];
            a += w4.x * p4.x + w4.y * p4.y + w4.z * p4.z + w4.w * p4.w;
        }
        qt_l[tid] = a;
    }
    __syncthreads();
    if (tid < 96) {
        const int d = tid >> 3, g = tid & 7;
        float p = 0.f;
        for (int j = g; j < ETn - 1; j += 8) p = fmaf(qt_l[j + 1], bas[d * 128 + j], p);
        red[tid] = p;
    } else {
        const int g2 = tid - 96;
        float p = 0.f;
#pragma unroll
        for (int k = 0; k < 4; ++k) p = fmaf(qp_l[g2 + 32 * k], bk[g2 + 32 * k], p);
        qbk_red[g2] = p;
    }
    __syncthreads();
    if (tid < NDEG) {
        const int d = tid;
        float s = red[d * 8 + 0] + red[d * 8 + 1] + red[d * 8 + 2] + red[d * 8 + 3]
                + red[d * 8 + 4] + red[d * 8 + 5] + red[d * 8 + 6] + red[d * 8 + 7];
        if (d == 0) {
            float qbk = 0.f;
#pragma unroll
            for (int k = 0; k < 32; ++k) qbk += qbk_red[k];
            s += qt_l[0] * lin_b[0] + qbk;
        }
        if (d == 1) s += qt_l[0] * lin_w[0];
        C[q * NDEG + d] = s * 0.08838834764831845f;   // 1/sqrt(128)
    }
}

// =================== K1d: fold wo (+bo) into layer-0 wih + zero sP ===================
__global__ __launch_bounds__(256) void k_fuse(
    const float* __restrict__ wih, const float* __restrict__ wo,
    const float* __restrict__ bo, const float* __restrict__ bih,
    float* __restrict__ Wt, float* __restrict__ bias2, float* __restrict__ sP)
{
    const int t = blockIdx.x * 256 + threadIdx.x;
    if (t < 768 * 32) {
        const int o = t >> 5, d = t & 31;
        const float4* wr4 = (const float4*)(wih + (size_t)o * 128);
        const float4* wc4 = (const float4*)(wo + (size_t)d * 128);
        float a = 0.f;
#pragma unroll
        for (int k = 0; k < 32; ++k) {
            const float4 r4 = wr4[k], c4 = wc4[k];
            a += r4.x * c4.x + r4.y * c4.y + r4.z * c4.z + r4.w * c4.w;
        }
        Wt[t] = a;
    } else if (t < 768 * 33) {
        const int o = t - 768 * 32;
        const float4* wr4 = (const float4*)(wih + (size_t)o * 128);
        const float4* bo4 = (const float4*)bo;
        float a = bih[o];
#pragma unroll
        for (int k = 0; k < 32; ++k) {
            const float4 r4 = wr4[k], b4 = bo4[k];
            a += r4.x * b4.x + r4.y * b4.y + r4.z * b4.z + r4.w * b4.w;
        }
        bias2[o] = a;
    } else if (t < 768 * 33 + Bn * LQn) {
        sP[t - 768 * 33] = 0.f;           // zero the atomic softmax-denominator buffer
    }
}

// =================== K1e: pack layer-1 wih to f16 (768 x 256) ===================
__global__ __launch_bounds__(256) void k_w16(
    const float* __restrict__ w, _Float16* __restrict__ w16)
{
    const int idx = blockIdx.x * 256 + threadIdx.x;
    if (idx < 768 * 256) w16[idx] = (_Float16)w[idx];
}

// =================== K2: attention — 8-way l-split (2 blocks/CU, 4 waves/SIMD) ===================
__global__ __launch_bounds__(512, 4) void k_attn(
    const float* __restrict__ x, const float* __restrict__ tsteps,
    const float* __restrict__ Cc, float* __restrict__ accP, float* __restrict__ sP)
{
    __shared__ __align__(16) char smem[4 * 128 * 36 * 4];   // 73728 B (xls/slab union)
    float4* xls  = (float4*)smem;
    float*  slabf = (float*)smem;
#define SLAB(s, qq, c) slabf[(((s) * 128) + (qq)) * 36 + (c)]
    const int tid = threadIdx.x;
    const int b = blockIdx.x >> 3, lsplit = blockIdx.x & 7;
    const int i = tid & 3, qt = (tid >> 2) & 31, ls2 = tid >> 7;
    const int qown = 4 * qt + i;
    const int u = tid & 127;

    float c[NDEG];
#pragma unroll
    for (int d = 0; d < NDEG; ++d) c[d] = Cc[qown * NDEG + d];

    const int l0 = lsplit * 512 + ls2 * 128;
    const float4* tg4 = (const float4*)(tsteps + (size_t)b * Ln + l0);
    const float4* xg  = (const float4*)(x + ((size_t)b * Ln + l0) * Dn);

    f32x2 acc2[4][4];
#pragma unroll
    for (int m = 0; m < 4; ++m)
#pragma unroll
        for (int e = 0; e < 4; ++e) { acc2[m][e].x = 0.f; acc2[m][e].y = 0.f; }
    float s_own = 0.f;

    float4 xr[4];
#pragma unroll
    for (int w = 0; w < 4; ++w) xr[w] = xg[u + 128 * w];

    for (int ch = 0; ch < 2; ++ch) {
        __syncthreads();
#pragma unroll
        for (int w = 0; w < 4; ++w) xls[ls2 * 512 + u + 128 * w] = xr[w];
        __syncthreads();
        if (ch < 1) {
            const int off = 512;
#pragma unroll
            for (int w = 0; w < 4; ++w) xr[w] = xg[off + u + 128 * w];
        }
        const float4* xrow = &xls[ls2 * 512];
        for (int k = 0; k < 16; ++k) {
            const float4 t4 = tg4[ch * 16 + k];
#pragma unroll
            for (int jj = 0; jj < 4; ++jj) {
                const float t = (jj == 0) ? t4.x : (jj == 1) ? t4.y : (jj == 2) ? t4.z : t4.w;
                float sc = c[NDEG - 1];
#pragma unroll
                for (int d = NDEG - 2; d >= 0; --d) sc = fmaf(sc, t, c[d]);
                const float pe = __expf(sc);
                s_own += pe;
                const float p0 = DPPF(pe, QP_B0);
                const float p1 = DPPF(pe, QP_B1);
                const float p2 = DPPF(pe, QP_B2);
                const float p3 = DPPF(pe, QP_B3);
                const int lrow = (k * 4 + jj) * 8;
                const float4 xa = xrow[lrow + 2 * i];
                const float4 xb = xrow[lrow + 2 * i + 1];
                f32x2 xa0; xa0.x = xa.x; xa0.y = xa.y;
                f32x2 xa1; xa1.x = xa.z; xa1.y = xa.w;
                f32x2 xb0; xb0.x = xb.x; xb0.y = xb.y;
                f32x2 xb1; xb1.x = xb.z; xb1.y = xb.w;
#define PKA(m, pv) { f32x2 pp; pp.x = (pv); pp.y = (pv); \
    acc2[m][0] = __builtin_elementwise_fma(pp, xa0, acc2[m][0]); \
    acc2[m][1] = __builtin_elementwise_fma(pp, xa1, acc2[m][1]); \
    acc2[m][2] = __builtin_elementwise_fma(pp, xb0, acc2[m][2]); \
    acc2[m][3] = __builtin_elementwise_fma(pp, xb1, acc2[m][3]); }
                PKA(0, p0) PKA(1, p1) PKA(2, p2) PKA(3, p3)
#undef PKA
            }
        }
    }
    __syncthreads();   // all xls reads complete; smem region reused as slab
#pragma unroll
    for (int m = 0; m < 4; ++m) {
        float4 f4a, f4b;
        f4a.x = acc2[m][0].x; f4a.y = acc2[m][0].y; f4a.z = acc2[m][1].x; f4a.w = acc2[m][1].y;
        f4b.x = acc2[m][2].x; f4b.y = acc2[m][2].y; f4b.z = acc2[m][3].x; f4b.w = acc2[m][3].y;
        *(float4*)&SLAB(ls2, 4 * qt + m, 8 * i)     = f4a;
        *(float4*)&SLAB(ls2, 4 * qt + m, 8 * i + 4) = f4b;
    }
    SLAB(ls2, qown, 32) = s_own;
    __syncthreads();
    const int q = tid & 127, part = tid >> 7;
#pragma unroll
    for (int j = 0; j < 2; ++j) {
        const int off = (part * 2 + j) * 4;
        float4 r  = *(float4*)&SLAB(0, q, off);
        float4 r1 = *(float4*)&SLAB(1, q, off);
        float4 r2 = *(float4*)&SLAB(2, q, off);
        float4 r3 = *(float4*)&SLAB(3, q, off);
        r.x += r1.x + r2.x + r3.x; r.y += r1.y + r2.y + r3.y;
        r.z += r1.z + r2.z + r3.z; r.w += r1.w + r2.w + r3.w;
        *(float4*)&accP[((((size_t)lsplit * Bn + b) * LQn + q) * 32) + off] = r;
    }
    if (part == 0) {
        atomicAdd(&sP[(size_t)b * LQn + q],
                  SLAB(0, q, 32) + SLAB(1, q, 32) + SLAB(2, q, 32) + SLAB(3, q, 32));
    }
#undef SLAB
}

// =================== K3a: GEMM layer-0: A = (sum_8 accP)/sP, K=32, pk core ===================
__global__ __launch_bounds__(256) void k_gemm_att(
    const float* __restrict__ accP, const float* __restrict__ sP,
    const float* __restrict__ Bm, const float* __restrict__ bias,
    float* __restrict__ Cm)
{
    __shared__ float4 A_l[64 * 8];
    __shared__ float4 B_l[64 * 8];
    const int tid = threadIdx.x;
    const int m0 = blockIdx.x * 64, n0 = blockIdx.y * 64;
    const int r0 = (tid >> 4) << 2, c0 = (tid & 15) << 2;
    f32x2 acc2[4][4];
#pragma unroll
    for (int a = 0; a < 4; ++a)
#pragma unroll
        for (int bb = 0; bb < 4; ++bb) { acc2[a][bb].x = 0.f; acc2[a][bb].y = 0.f; }
    const float4* Ag = (const float4*)accP;
    const float4* Bg = (const float4*)Bm;

#pragma unroll
    for (int w = 0; w < 2; ++w) {
        const int idx = tid + w * 256;
        const int row = idx >> 3, c4 = idx & 7;
        const int sc = (c4 + row + (row >> 2)) & 7;
        const int m = m0 + row;
        float4 av = Ag[(size_t)m * 8 + c4];
#pragma unroll
        for (int s = 1; s < 8; ++s) {
            const float4 as = Ag[((size_t)s * 8192 + m) * 8 + c4];
            av.x += as.x; av.y += as.y; av.z += as.z; av.w += as.w;
        }
        const float inv = 1.f / sP[m];
        av.x *= inv; av.y *= inv; av.z *= inv; av.w *= inv;
        A_l[row * 8 + sc] = av;
        B_l[row * 8 + sc] = Bg[(size_t)(n0 + row) * 8 + c4];
    }
    __syncthreads();
#pragma unroll
    for (int k4 = 0; k4 < 8; ++k4) {
        float4 av[4], bv[4];
#pragma unroll
        for (int j = 0; j < 4; ++j) {
            const int ra = r0 + j;
            av[j] = A_l[ra * 8 + ((k4 + ra + (ra >> 2)) & 7)];
        }
#pragma unroll
        for (int j = 0; j < 4; ++j) {
            const int rb = c0 + j;
            bv[j] = B_l[rb * 8 + ((k4 + rb + (rb >> 2)) & 7)];
        }
#pragma unroll
        for (int ri = 0; ri < 4; ++ri) {
            f32x2 alo; alo.x = av[ri].x; alo.y = av[ri].y;
            f32x2 ahi; ahi.x = av[ri].z; ahi.y = av[ri].w;
#pragma unroll
            for (int ci = 0; ci < 4; ++ci) {
                f32x2 blo; blo.x = bv[ci].x; blo.y = bv[ci].y;
                f32x2 bhi; bhi.x = bv[ci].z; bhi.y = bv[ci].w;
                acc2[ri][ci] = __builtin_elementwise_fma(alo, blo, acc2[ri][ci]);
                acc2[ri][ci] = __builtin_elementwise_fma(ahi, bhi, acc2[ri][ci]);
            }
        }
    }
#pragma unroll
    for (int ri = 0; ri < 4; ++ri) {
        float4 o4;
        o4.x = acc2[ri][0].x + acc2[ri][0].y + bias[n0 + c0 + 0];
        o4.y = acc2[ri][1].x + acc2[ri][1].y + bias[n0 + c0 + 1];
        o4.z = acc2[ri][2].x + acc2[ri][2].y + bias[n0 + c0 + 2];
        o4.w = acc2[ri][3].x + acc2[ri][3].y + bias[n0 + c0 + 3];
        *(float4*)&Cm[(size_t)(m0 + r0 + ri) * 768 + n0 + c0] = o4;
    }
}

// =================== K3b: layer-1 GEMM via MFMA f16 (verified R16) ===================
__global__ __launch_bounds__(256) void k_gemm16(
    const _Float16* __restrict__ g0, const _Float16* __restrict__ w16,
    const float* __restrict__ bias, float* __restrict__ Cm)
{
    const int tid = threadIdx.x;
    const int wave = tid >> 6, lane = tid & 63;
    const int m0 = blockIdx.x * 64 + wave * 16;
    const int n0 = blockIdx.y * 64;
    const int koff = 8 * (lane >> 4);

    const _Float16* Ab  = g0 + (size_t)(m0 + (lane & 15)) * 256 + koff;
    const _Float16* Bb0 = w16 + (size_t)(n0 +  0 + (lane & 15)) * 256 + koff;
    const _Float16* Bb1 = w16 + (size_t)(n0 + 16 + (lane & 15)) * 256 + koff;
    const _Float16* Bb2 = w16 + (size_t)(n0 + 32 + (lane & 15)) * 256 + koff;
    const _Float16* Bb3 = w16 + (size_t)(n0 + 48 + (lane & 15)) * 256 + koff;

    f32x4 acc0 = {0.f, 0.f, 0.f, 0.f}, acc1 = acc0, acc2 = acc0, acc3 = acc0;
#pragma unroll
    for (int k0 = 0; k0 < 256; k0 += 32) {
        const f16x8 a  = *(const f16x8*)(Ab  + k0);
        const f16x8 b0 = *(const f16x8*)(Bb0 + k0);
        const f16x8 b1 = *(const f16x8*)(Bb1 + k0);
        const f16x8 b2 = *(const f16x8*)(Bb2 + k0);
        const f16x8 b3 = *(const f16x8*)(Bb3 + k0);
        acc0 = __builtin_amdgcn_mfma_f32_16x16x32_f16(a, b0, acc0, 0, 0, 0);
        acc1 = __builtin_amdgcn_mfma_f32_16x16x32_f16(a, b1, acc1, 0, 0, 0);
        acc2 = __builtin_amdgcn_mfma_f32_16x16x32_f16(a, b2, acc2, 0, 0, 0);
        acc3 = __builtin_amdgcn_mfma_f32_16x16x32_f16(a, b3, acc3, 0, 0, 0);
    }
    const int mr = m0 + (lane >> 4) * 4;
    const int nc = lane & 15;
#pragma unroll
    for (int r = 0; r < 4; ++r) {
        Cm[(size_t)(mr + r) * 768 + n0 +  0 + nc] = acc0[r] + bias[n0 +  0 + nc];
        Cm[(size_t)(mr + r) * 768 + n0 + 16 + nc] = acc1[r] + bias[n0 + 16 + nc];
        Cm[(size_t)(mr + r) * 768 + n0 + 32 + nc] = acc2[r] + bias[n0 + 32 + nc];
        Cm[(size_t)(mr + r) * 768 + n0 + 48 + nc] = acc3[r] + bias[n0 + 48 + nc];
    }
}

// =================== K4: GRU — R19 structure (77-78µs, best measured), seq_out f16 ===================
// 256 threads: (j = tid>>1, q = tid&1 = 64-wide slice). One block per (b,dir). Grid 128.
// f16 weights 48 VGPRs, resident at the 256-thr/(256,1) ~124-VGPR budget (the ONLY
// allocator shape that grants it). Final configuration after 20 rounds of exploration:
// NB=2 (+88µs), 1024thr (+42), AGPR stash (+85), dual-chain block (+40), dual-acc (±0)
// all measured worse; the 128-step serial chain at ~1450 cyc/step is the structural floor.
__global__ __launch_bounds__(256, 1) void k_gru(
    const float* __restrict__ gi, const float* __restrict__ whh,
    const float* __restrict__ bhh, _Float16* __restrict__ seq_out,
    float* __restrict__ final_out)
{
    __shared__ _Float16 h16[2][Hn];
    __shared__ float    h32[2][Hn];
    const int tid = threadIdx.x;
    const int b = blockIdx.x >> 1, dir = blockIdx.x & 1;
    const int j = tid >> 1, q = tid & 1;

    f16x2 wr[32], wz[32], wn[32];
    {
        const float* wb = whh + ((size_t)dir * G3n + j) * Hn + 64 * q;
        const f32x2* p0 = (const f32x2*)(wb);
        const f32x2* p1 = (const f32x2*)(wb + (size_t)128 * Hn);
        const f32x2* p2 = (const f32x2*)(wb + (size_t)256 * Hn);
#pragma unroll
        for (int k = 0; k < 32; ++k) {
            f32x2 a = p0[k], z2 = p1[k], c2 = p2[k];
            wr[k].x = (_Float16)a.x;  wr[k].y = (_Float16)a.y;
            wz[k].x = (_Float16)z2.x; wz[k].y = (_Float16)z2.y;
            wn[k].x = (_Float16)c2.x; wn[k].y = (_Float16)c2.y;
        }
    }
#pragma unroll
    for (int k = 0; k < 32; ++k) {
        asm volatile("" : "+v"(wr[k]));
        asm volatile("" : "+v"(wz[k]));
        asm volatile("" : "+v"(wn[k]));
    }
    const float bhr = bhh[dir * G3n + j];
    const float bhz = bhh[dir * G3n + 128 + j];
    const float bhn = bhh[dir * G3n + 256 + j];

    if (tid < Hn) {
        h32[0][tid] = 0.f; h32[1][tid] = 0.f;
        h16[0][tid] = (_Float16)0.f; h16[1][tid] = (_Float16)0.f;
    }
    __syncthreads();

    const long sstride = dir ? -768 : 768;
    const float* gptr = gi + (size_t)b * LQn * 768 + dir * G3n + j
                        + (size_t)(dir ? LQn - 1 : 0) * 768;

    int cur = 0;
    float hlast = 0.f;

    auto gstep = [&](const float gir, const float giz, const float gin, const int step) {
        const float hold = h32[cur][j];
        const float4* hb4 = (const float4*)(&h16[cur][64 * q]);
        float srA = 0.f, szA = 0.f, snA = 0.f;
        float srB = 0.f, szB = 0.f, snB = 0.f;
#pragma unroll
        for (int k2 = 0; k2 < 4; ++k2) {
            float4 hv = hb4[k2];
            f16x2 h0 = *(f16x2*)&hv.x;
            f16x2 h1 = *(f16x2*)&hv.y;
            f16x2 h2 = *(f16x2*)&hv.z;
            f16x2 h3 = *(f16x2*)&hv.w;
            asm("v_dot2_f32_f16 %0, %1, %2, %0" : "+v"(srA) : "v"(wr[4 * k2 + 0]), "v"(h0));
            asm("v_dot2_f32_f16 %0, %1, %2, %0" : "+v"(szA) : "v"(wz[4 * k2 + 0]), "v"(h0));
            asm("v_dot2_f32_f16 %0, %1, %2, %0" : "+v"(snA) : "v"(wn[4 * k2 + 0]), "v"(h0));
            asm("v_dot2_f32_f16 %0, %1, %2, %0" : "+v"(srA) : "v"(wr[4 * k2 + 1]), "v"(h1));
            asm("v_dot2_f32_f16 %0, %1, %2, %0" : "+v"(szA) : "v"(wz[4 * k2 + 1]), "v"(h1));
            asm("v_dot2_f32_f16 %0, %1, %2, %0" : "+v"(snA) : "v"(wn[4 * k2 + 1]), "v"(h1));
            asm("v_dot2_f32_f16 %0, %1, %2, %0" : "+v"(srA) : "v"(wr[4 * k2 + 2]), "v"(h2));
            asm("v_dot2_f32_f16 %0, %1, %2, %0" : "+v"(szA) : "v"(wz[4 * k2 + 2]), "v"(h2));
            asm("v_dot2_f32_f16 %0, %1, %2, %0" : "+v"(snA) : "v"(wn[4 * k2 + 2]), "v"(h2));
            asm("v_dot2_f32_f16 %0, %1, %2, %0" : "+v"(srA) : "v"(wr[4 * k2 + 3]), "v"(h3));
            asm("v_dot2_f32_f16 %0, %1, %2, %0" : "+v"(szA) : "v"(wz[4 * k2 + 3]), "v"(h3));
            asm("v_dot2_f32_f16 %0, %1, %2, %0" : "+v"(snA) : "v"(wn[4 * k2 + 3]), "v"(h3));
        }
#pragma unroll
        for (int k2 = 4; k2 < 8; ++k2) {
            float4 hv = hb4[k2];
            f16x2 h0 = *(f16x2*)&hv.x;
            f16x2 h1 = *(f16x2*)&hv.y;
            f16x2 h2 = *(f16x2*)&hv.z;
            f16x2 h3 = *(f16x2*)&hv.w;
            asm("v_dot2_f32_f16 %0, %1, %2, %0" : "+v"(srB) : "v"(wr[4 * k2 + 0]), "v"(h0));
            asm("v_dot2_f32_f16 %0, %1, %2, %0" : "+v"(szB) : "v"(wz[4 * k2 + 0]), "v"(h0));
            asm("v_dot2_f32_f16 %0, %1, %2, %0" : "+v"(snB) : "v"(wn[4 * k2 + 0]), "v"(h0));
            asm("v_dot2_f32_f16 %0, %1, %2, %0" : "+v"(srB) : "v"(wr[4 * k2 + 1]), "v"(h1));
            asm("v_dot2_f32_f16 %0, %1, %2, %0" : "+v"(szB) : "v"(wz[4 * k2 + 1]), "v"(h1));
            asm("v_dot2_f32_f16 %0, %1, %2, %0" : "+v"(snB) : "v"(wn[4 * k2 + 1]), "v"(h1));
            asm("v_dot2_f32_f16 %0, %1, %2, %0" : "+v"(srB) : "v"(wr[4 * k2 + 2]), "v"(h2));
            asm("v_dot2_f32_f16 %0, %1, %2, %0" : "+v"(szB) : "v"(wz[4 * k2 + 2]), "v"(h2));
            asm("v_dot2_f32_f16 %0, %1, %2, %0" : "+v"(snB) : "v"(wn[4 * k2 + 2]), "v"(h2));
            asm("v_dot2_f32_f16 %0, %1, %2, %0" : "+v"(srB) : "v"(wr[4 * k2 + 3]), "v"(h3));
            asm("v_dot2_f32_f16 %0, %1, %2, %0" : "+v"(szB) : "v"(wz[4 * k2 + 3]), "v"(h3));
            asm("v_dot2_f32_f16 %0, %1, %2, %0" : "+v"(snB) : "v"(wn[4 * k2 + 3]), "v"(h3));
        }
        float sr = srA + srB, sz = szA + szB, sn = snA + snB;
        sr += DPPF(sr, QP_XOR1);
        sz += DPPF(sz, QP_XOR1);
        sn += DPPF(sn, QP_XOR1);
        const float r = 1.f / (1.f + __expf(-(gir + sr + bhr)));
        const float z = 1.f / (1.f + __expf(-(giz + sz + bhz)));
        const float nx = gin + r * (sn + bhn);
        const float n = 1.f - 2.f / (1.f + __expf(2.f * nx));   // tanh
        const float hn = n + z * (hold - n);
        if (q == 0) {
            h32[cur ^ 1][j] = hn;
            h16[cur ^ 1][j] = (_Float16)hn;
            if (seq_out) {
                const int l = dir ? (LQn - 1 - step) : step;
                seq_out[((size_t)(b * LQn + l)) * (2 * Hn) + dir * Hn + j] = (_Float16)hn;
            }
        }
        hlast = hn;
        cur ^= 1;
        asm volatile("s_waitcnt lgkmcnt(0)\n\ts_barrier" ::: "memory");
    };

    float gA[3], gB[3];
#define GLD(dst, s) { const long o = (long)(s) * sstride; \
    dst[0] = gptr[o]; dst[1] = gptr[o + 128]; dst[2] = gptr[o + 256]; }
    GLD(gA, 0) GLD(gB, 1)
    for (int s0 = 0; s0 < LQn; s0 += 2) {
        gstep(gA[0], gA[1], gA[2], s0);
        { const int sn2 = (s0 + 2 < LQn) ? s0 + 2 : LQn - 1; GLD(gA, sn2) }
        gstep(gB[0], gB[1], gB[2], s0 + 1);
        { const int sn2 = (s0 + 3 < LQn) ? s0 + 3 : LQn - 1; GLD(gB, sn2) }
    }
#undef GLD
    if (final_out && q == 0) final_out[b * 2 * Hn + dir * Hn + j] = hlast;
}

// =================== K5: classifier MLP ===================
__global__ __launch_bounds__(256) void k_cls(
    const float* __restrict__ cls_in,
    const float* __restrict__ c1w, const float* __restrict__ c1b,
    const float* __restrict__ c2w, const float* __restrict__ c2b,
    const float* __restrict__ c3w, const float* __restrict__ c3b,
    float* __restrict__ out)
{
    __shared__ float ci[256], y1[128], y2[64];
    const int b = blockIdx.x, tid = threadIdx.x;
    ci[tid] = cls_in[b * 256 + tid];
    __syncthreads();
    if (tid < 128) { float a = c1b[tid]; for (int i = 0; i < 256; ++i) a += ci[i] * c1w[i * 128 + tid]; y1[tid] = a; }
    __syncthreads();
    if (tid < 64)  { float a = c2b[tid]; for (int i = 0; i < 128; ++i) a += y1[i] * c2w[i * 64 + tid];  y2[tid] = a; }
    __syncthreads();
    if (tid < 6)   { float a = c3b[tid]; for (int i = 0; i < 64; ++i)  a += y2[i] * c3w[i * 6 + tid];   out[b * 6 + tid] = a; }
}

// =================== launch ===================
extern "C" void kernel_launch(void* const* d_in, const int* in_sizes, int n_in,
                              void* d_out, int out_size, void* d_ws, size_t ws_size,
                              hipStream_t stream)
{
    const float* x        = (const float*)d_in[0];
    const float* tsteps   = (const float*)d_in[1];
    const float* qtimes   = (const float*)d_in[2];
    const float* lin_w    = (const float*)d_in[3];
    const float* lin_b    = (const float*)d_in[4];
    const float* per_w    = (const float*)d_in[5];
    const float* per_b    = (const float*)d_in[6];
    const float* wq       = (const float*)d_in[7];
    const float* bq       = (const float*)d_in[8];
    const float* wk       = (const float*)d_in[9];
    const float* bk       = (const float*)d_in[10];
    const float* wo       = (const float*)d_in[11];
    const float* bo       = (const float*)d_in[12];
    const float* g0_wih   = (const float*)d_in[13];
    const float* g0_whh   = (const float*)d_in[14];
    const float* g0_bih   = (const float*)d_in[15];
    const float* g0_bhh   = (const float*)d_in[16];
    const float* g1_wih   = (const float*)d_in[17];
    const float* g1_whh   = (const float*)d_in[18];
    const float* g1_bih   = (const float*)d_in[19];
    const float* g1_bhh   = (const float*)d_in[20];
    const float* c1w      = (const float*)d_in[21];
    const float* c1b      = (const float*)d_in[22];
    const float* c2w      = (const float*)d_in[23];
    const float* c2b      = (const float*)d_in[24];
    const float* c3w      = (const float*)d_in[25];
    const float* c3b      = (const float*)d_in[26];
    float* out = (float*)d_out;
    float* ws  = (float*)d_ws;

    float* Cws   = ws + WS_C;
    float* Wt    = ws + WS_WT;
    float* bias2 = ws + WS_B2;
    float* clsin = ws + WS_CLS;
    float* accP  = ws + WS_ACCP;
    float* sPb   = ws + WS_SP;                     // 8192 floats, aliases clsin head (disjoint lifetime)
    float* gibuf = ws + WS_GI;
    _Float16* g0f16 = (_Float16*)(ws + WS_G0);     // after accP dead
    _Float16* w16b  = (_Float16*)(ws + WS_W16);    // after accP dead

    k_coef<<<128, 128, 0, stream>>>(qtimes, lin_w, lin_b, per_w, per_b, wq, bq, wk, bk, Cws);
    k_fuse<<<131, 256, 0, stream>>>(g0_wih, wo, bo, g0_bih, Wt, bias2, sPb);
    k_attn<<<512, 512, 0, stream>>>(x, tsteps, Cws, accP, sPb);

    // layer 0: gi = att @ Wt^T + bias2 (att assembled in-GEMM from 8-slice accP / atomic sP)
    k_gemm_att<<<dim3(128, 12), 256, 0, stream>>>(accP, sPb, Wt, bias2, gibuf);
    // pack layer-1 weights to f16 (accP now dead; overlaps gru0)
    k_w16<<<768, 256, 0, stream>>>(g1_wih, w16b);
    k_gru<<<128, 256, 0, stream>>>(gibuf, g0_whh, g0_bhh, g0f16, nullptr);

    // layer 1: gi = g0f16 @ w16^T + bih  (MFMA f16)
    k_gemm16<<<dim3(128, 12), 256, 0, stream>>>(g0f16, w16b, g1_bih, gibuf);
    k_gru<<<128, 256, 0, stream>>>(gibuf, g1_whh, g1_bhh, nullptr, clsin);

    k_cls<<<64, 256, 0, stream>>>(clsin, c1w, c1b, c2w, c2b, c3w, c3b, out);
}